// Round 5
// baseline (884.776 us; speedup 1.0000x reference)
//
#include <hip/hip_runtime.h>
#include <hip/hip_fp16.h>
#include <math.h>

#define KNN 16
#define CH 64
#define HID 16
#define GRID_BLKS 768   // 3 blocks/CU on 256 CUs; capacity is 4/CU (VGPR<=128,
                        // LDS 9.4KB) so ALL blocks are co-resident -> manual
                        // grid barrier cannot deadlock.

__device__ __forceinline__ float sigmoidf_(float x) {
    return 1.0f / (1.0f + __expf(-x));
}

// pack two fp32 into bf16x2 (RNE), a in low16, b in high16
__device__ __forceinline__ unsigned int pack_bf2(float a, float b) {
    unsigned int ua = __float_as_uint(a), ub = __float_as_uint(b);
    ua = (ua + 0x7FFFu + ((ua >> 16) & 1u)) >> 16;
    ub = (ub + 0x7FFFu + ((ub >> 16) & 1u)) & 0xFFFF0000u;
    return ua | ub;
}

// unpack 4 packed bf16 -> float4
__device__ __forceinline__ float4 bf4_to_f4(unsigned int lo, unsigned int hi) {
    float4 r;
    r.x = __uint_as_float(lo << 16);
    r.y = __uint_as_float(lo & 0xFFFF0000u);
    r.z = __uint_as_float(hi << 16);
    r.w = __uint_as_float(hi & 0xFFFF0000u);
    return r;
}

// f16 pack/unpack for the gate (gate in (0,1): f16 rel err < 2^-11)
__device__ __forceinline__ unsigned int pack_h2(float a, float b) {
    __half2 h = __floats2half2_rn(a, b);
    return *(unsigned int*)&h;
}
__device__ __forceinline__ float2 unpack_h2(unsigned int u) {
    __half2 h;
    *(unsigned int*)&h = u;
    return __half22float2(h);
}

// Manual grid-wide barrier (R4 lesson: hipLaunchCooperativeKernel silently
// no-ops under the harness's graph capture -> output stayed zero). Works with
// a PLAIN launch: release-fence (agent scope: L2 writeback, required because
// per-XCD L2s are not coherent), arrive via device-scope atomic, thread-0
// acquire-spin, then acquire-fence. Counters are memset to 0 on the stream
// before the kernel each launch, so a simple "< NBLK" wait is correct.
__device__ __forceinline__ void grid_barrier(unsigned int* cnt) {
    __threadfence();                       // release this thread's writes
    __syncthreads();
    if (threadIdx.x == 0) {
        __hip_atomic_fetch_add(cnt, 1u, __ATOMIC_RELEASE, __HIP_MEMORY_SCOPE_AGENT);
        while (__hip_atomic_load(cnt, __ATOMIC_ACQUIRE, __HIP_MEMORY_SCOPE_AGENT)
               < (unsigned)GRID_BLKS)
            __builtin_amdgcn_s_sleep(1);
    }
    __syncthreads();
    __threadfence();                       // acquire: drop stale cached lines
}

// R5: whole pipeline in ONE persistent kernel with manual grid barriers.
// R3 showed kA1 alone is 56 us of a 177 us pipeline — the rest is 4 small
// kernels + launch gaps. Phase A is the FUSED R0 shape (gathers + MLP + own
// fp32 rows + rowstat; R3 proved splitting costs bandwidth: 1.98->1.70 TB/s)
// but stores the f16 gate (12.8 MB) instead of fp32 outse (25.6 MB); phase C
// reconstructs out = x * gate * sig (R3-proven numerics, absmax 0.0156).
// No nt hints anywhere (R2: they bypass L3 and regress).
__global__ __launch_bounds__(256, 3) void kFused(
        const float4* __restrict__ xv,
        const float* __restrict__ W1, const float* __restrict__ b1,
        const float* __restrict__ W2, const float* __restrict__ b2,
        const float* __restrict__ conv_w,
        const int2* __restrict__ idx2, const int4* __restrict__ idxv,
        const int* __restrict__ conv_idx,
        uint2* xb, uint4* gateh, float2* rowstat, float2* z,
        float4* out, unsigned int* barcnt, int n) {
    __shared__ float4 w1a[128];   // w1a[h*8+s] = W1[(8s+0..3)][h]
    __shared__ float4 w1b[128];   // w1b[h*8+s] = W1[(8s+4..7)][h]
    __shared__ float4 w2q[256];   // float4 copy of W2 (16x64 row-major)
    __shared__ float cw[54];
    __shared__ float sgate[256];
    int t = threadIdx.x;

    // stage all LDS-resident params once
    if (t < 128) {
        int h = t >> 3, s = t & 7;
        float4 a, b;
        a.x = W1[(8 * s + 0) * HID + h];
        a.y = W1[(8 * s + 1) * HID + h];
        a.z = W1[(8 * s + 2) * HID + h];
        a.w = W1[(8 * s + 3) * HID + h];
        b.x = W1[(8 * s + 4) * HID + h];
        b.y = W1[(8 * s + 5) * HID + h];
        b.z = W1[(8 * s + 6) * HID + h];
        b.w = W1[(8 * s + 7) * HID + h];
        w1a[t] = a;
        w1b[t] = b;
    }
    w2q[t] = ((const float4*)W2)[t];
    if (t < 54) cw[t] = conv_w[t];
    __syncthreads();

    // ---------------- phase X: bf16 gather table ----------------
    int n16 = n * 16;
    for (int i = blockIdx.x * 256 + t; i < n16; i += GRID_BLKS * 256) {
        float4 v = xv[i];
        uint2 r;
        r.x = pack_bf2(v.x, v.y);
        r.y = pack_bf2(v.z, v.w);
        xb[i] = r;
    }
    grid_barrier(&barcnt[0]);

    // ---------------- phase A: gathers + MLP -> gate + rowstat ----------------
    const uint4* xb4 = (const uint4*)xb;
    int sub = t & 7;
    float b1a = b1[sub], b1b = b1[sub + 8];
    float4 bq0 = ((const float4*)b2)[2 * sub];
    float4 bq1 = ((const float4*)b2)[2 * sub + 1];
    for (int p0 = blockIdx.x * 32; p0 < n; p0 += GRID_BLKS * 32) {
        int p = p0 + (t >> 3);
        if (p < n) {   // uniform across each 8-lane group
            int2 jp = idx2[(size_t)p * 8 + sub];
            int jA[8], jB[8];
            #pragma unroll
            for (int s = 0; s < 8; ++s) {
                jA[s] = __shfl(jp.x, s, 8);
                jB[s] = __shfl(jp.y, s, 8);
            }

            // batch-issue all 16 gathers + own fp32 rows, pin with sched_barrier
            uint4 va[8], vb[8];
            #pragma unroll
            for (int s = 0; s < 8; ++s) va[s] = xb4[(size_t)jA[s] * 8 + sub];
            #pragma unroll
            for (int s = 0; s < 8; ++s) vb[s] = xb4[(size_t)jB[s] * 8 + sub];
            float4 own0 = xv[(size_t)p * 16 + 2 * sub];
            float4 own1 = xv[(size_t)p * 16 + 2 * sub + 1];
            __builtin_amdgcn_sched_barrier(0);

            float4 sumLo, sumHi, mxLo, mxHi;
            {
                float4 lo = bf4_to_f4(va[0].x, va[0].y);
                float4 hi = bf4_to_f4(va[0].z, va[0].w);
                sumLo = lo; mxLo = lo; sumHi = hi; mxHi = hi;
            }
            #pragma unroll
            for (int s = 1; s < 8; ++s) {
                float4 lo = bf4_to_f4(va[s].x, va[s].y);
                float4 hi = bf4_to_f4(va[s].z, va[s].w);
                sumLo.x += lo.x; sumLo.y += lo.y; sumLo.z += lo.z; sumLo.w += lo.w;
                sumHi.x += hi.x; sumHi.y += hi.y; sumHi.z += hi.z; sumHi.w += hi.w;
                mxLo.x = fmaxf(mxLo.x, lo.x); mxLo.y = fmaxf(mxLo.y, lo.y);
                mxLo.z = fmaxf(mxLo.z, lo.z); mxLo.w = fmaxf(mxLo.w, lo.w);
                mxHi.x = fmaxf(mxHi.x, hi.x); mxHi.y = fmaxf(mxHi.y, hi.y);
                mxHi.z = fmaxf(mxHi.z, hi.z); mxHi.w = fmaxf(mxHi.w, hi.w);
            }
            #pragma unroll
            for (int s = 0; s < 8; ++s) {
                float4 lo = bf4_to_f4(vb[s].x, vb[s].y);
                float4 hi = bf4_to_f4(vb[s].z, vb[s].w);
                sumLo.x += lo.x; sumLo.y += lo.y; sumLo.z += lo.z; sumLo.w += lo.w;
                sumHi.x += hi.x; sumHi.y += hi.y; sumHi.z += hi.z; sumHi.w += hi.w;
                mxLo.x = fmaxf(mxLo.x, lo.x); mxLo.y = fmaxf(mxLo.y, lo.y);
                mxLo.z = fmaxf(mxLo.z, lo.z); mxLo.w = fmaxf(mxLo.w, lo.w);
                mxHi.x = fmaxf(mxHi.x, hi.x); mxHi.y = fmaxf(mxHi.y, hi.y);
                mxHi.z = fmaxf(mxHi.z, hi.z); mxHi.w = fmaxf(mxHi.w, hi.w);
            }
            const float inv_k = 1.0f / KNN;
            float4 meLo = {sumLo.x * inv_k, sumLo.y * inv_k, sumLo.z * inv_k, sumLo.w * inv_k};
            float4 meHi = {sumHi.x * inv_k, sumHi.y * inv_k, sumHi.z * inv_k, sumHi.w * inv_k};

            float Hm_a, Hm_b, Hx_a, Hx_b;
            {
                float A[8], B[8];
                #pragma unroll
                for (int h = 0; h < 8; ++h) {
                    float4 wa = w1a[h * 8 + sub], wb = w1b[h * 8 + sub];
                    A[h] = meLo.x * wa.x + meLo.y * wa.y + meLo.z * wa.z + meLo.w * wa.w
                         + meHi.x * wb.x + meHi.y * wb.y + meHi.z * wb.z + meHi.w * wb.w;
                    float4 wa2 = w1a[(h + 8) * 8 + sub], wb2 = w1b[(h + 8) * 8 + sub];
                    B[h] = meLo.x * wa2.x + meLo.y * wa2.y + meLo.z * wa2.z + meLo.w * wa2.w
                         + meHi.x * wb2.x + meHi.y * wb2.y + meHi.z * wb2.z + meHi.w * wb2.w;
                }
                #pragma unroll
                for (int m = 4; m >= 1; m >>= 1) {
                    bool hi = (sub & m) != 0;
                    #pragma unroll
                    for (int i = 0; i < m; ++i) {
                        float sA = hi ? A[i] : A[i + m], kA_ = hi ? A[i + m] : A[i];
                        A[i] = kA_ + __shfl_xor(sA, m);
                        float sB = hi ? B[i] : B[i + m], kB_ = hi ? B[i + m] : B[i];
                        B[i] = kB_ + __shfl_xor(sB, m);
                    }
                }
                Hm_a = A[0]; Hm_b = B[0];
            }
            {
                float A[8], B[8];
                #pragma unroll
                for (int h = 0; h < 8; ++h) {
                    float4 wa = w1a[h * 8 + sub], wb = w1b[h * 8 + sub];
                    A[h] = mxLo.x * wa.x + mxLo.y * wa.y + mxLo.z * wa.z + mxLo.w * wa.w
                         + mxHi.x * wb.x + mxHi.y * wb.y + mxHi.z * wb.z + mxHi.w * wb.w;
                    float4 wa2 = w1a[(h + 8) * 8 + sub], wb2 = w1b[(h + 8) * 8 + sub];
                    B[h] = mxLo.x * wa2.x + mxLo.y * wa2.y + mxLo.z * wa2.z + mxLo.w * wa2.w
                         + mxHi.x * wb2.x + mxHi.y * wb2.y + mxHi.z * wb2.z + mxHi.w * wb2.w;
                }
                #pragma unroll
                for (int m = 4; m >= 1; m >>= 1) {
                    bool hi = (sub & m) != 0;
                    #pragma unroll
                    for (int i = 0; i < m; ++i) {
                        float sA = hi ? A[i] : A[i + m], kA_ = hi ? A[i + m] : A[i];
                        A[i] = kA_ + __shfl_xor(sA, m);
                        float sB = hi ? B[i] : B[i + m], kB_ = hi ? B[i + m] : B[i];
                        B[i] = kB_ + __shfl_xor(sB, m);
                    }
                }
                Hx_a = A[0]; Hx_b = B[0];
            }
            float H_a = fmaxf(Hm_a + b1a, 0.0f) + fmaxf(Hx_a + b1a, 0.0f);
            float H_b = fmaxf(Hm_b + b1b, 0.0f) + fmaxf(Hx_b + b1b, 0.0f);

            float4 a0 = {0.f, 0.f, 0.f, 0.f}, a1 = {0.f, 0.f, 0.f, 0.f};
            #pragma unroll
            for (int h = 0; h < 8; ++h) {
                float Hh = __shfl(H_a, h, 8);
                float4 w0 = w2q[h * 16 + 2 * sub], w1v = w2q[h * 16 + 2 * sub + 1];
                a0.x += Hh * w0.x; a0.y += Hh * w0.y; a0.z += Hh * w0.z; a0.w += Hh * w0.w;
                a1.x += Hh * w1v.x; a1.y += Hh * w1v.y; a1.z += Hh * w1v.z; a1.w += Hh * w1v.w;
            }
            #pragma unroll
            for (int h = 0; h < 8; ++h) {
                float Hh = __shfl(H_b, h, 8);
                float4 w0 = w2q[(h + 8) * 16 + 2 * sub], w1v = w2q[(h + 8) * 16 + 2 * sub + 1];
                a0.x += Hh * w0.x; a0.y += Hh * w0.y; a0.z += Hh * w0.z; a0.w += Hh * w0.w;
                a1.x += Hh * w1v.x; a1.y += Hh * w1v.y; a1.z += Hh * w1v.z; a1.w += Hh * w1v.w;
            }

            float s0 = sigmoidf_(a0.x + 2.0f * bq0.x);
            float s1 = sigmoidf_(a0.y + 2.0f * bq0.y);
            float s2 = sigmoidf_(a0.z + 2.0f * bq0.z);
            float s3 = sigmoidf_(a0.w + 2.0f * bq0.w);
            float s4 = sigmoidf_(a1.x + 2.0f * bq1.x);
            float s5 = sigmoidf_(a1.y + 2.0f * bq1.y);
            float s6 = sigmoidf_(a1.z + 2.0f * bq1.z);
            float s7 = sigmoidf_(a1.w + 2.0f * bq1.w);
            uint4 gv;
            gv.x = pack_h2(s0, s1);
            gv.y = pack_h2(s2, s3);
            gv.z = pack_h2(s4, s5);
            gv.w = pack_h2(s6, s7);
            gateh[(size_t)p * 8 + sub] = gv;

            // rowstat from fp32 own row * gate (exact outse values)
            float o0 = own0.x * s0, o1 = own0.y * s1;
            float o2 = own0.z * s2, o3 = own0.w * s3;
            float o4 = own1.x * s4, o5 = own1.y * s5;
            float o6 = own1.z * s6, o7 = own1.w * s7;
            float sm = (o0 + o1) + (o2 + o3) + ((o4 + o5) + (o6 + o7));
            float sx = fmaxf(fmaxf(fmaxf(o0, o1), fmaxf(o2, o3)),
                             fmaxf(fmaxf(o4, o5), fmaxf(o6, o7)));
            #pragma unroll
            for (int m = 4; m >= 1; m >>= 1) {
                sm += __shfl_xor(sm, m);
                sx = fmaxf(sx, __shfl_xor(sx, m));
            }
            if (sub == 0) rowstat[p] = make_float2(sm * (1.0f / 64.0f), sx);
        }
    }
    grid_barrier(&barcnt[1]);

    // ---------------- phase B: z = (mean_k rowmean, max_k rowmax) ----------------
    for (int q = blockIdx.x * 256 + t; q < 2 * n; q += GRID_BLKS * 256) {
        int i = q >> 1, half = q & 1;
        int4 a = idxv[(size_t)i * 4 + half * 2];
        int4 b = idxv[(size_t)i * 4 + half * 2 + 1];
        float2 s0 = rowstat[a.x], s1 = rowstat[a.y], s2 = rowstat[a.z], s3 = rowstat[a.w];
        float2 s4 = rowstat[b.x], s5 = rowstat[b.y], s6 = rowstat[b.z], s7 = rowstat[b.w];
        float zm = (s0.x + s1.x) + (s2.x + s3.x) + ((s4.x + s5.x) + (s6.x + s7.x));
        float zx = fmaxf(fmaxf(fmaxf(s0.y, s1.y), fmaxf(s2.y, s3.y)),
                         fmaxf(fmaxf(s4.y, s5.y), fmaxf(s6.y, s7.y)));
        zm += __shfl_xor(zm, 1);
        zx = fmaxf(zx, __shfl_xor(zx, 1));
        if (half == 0) z[i] = make_float2(zm * (1.0f / 16.0f), zx);
    }
    grid_barrier(&barcnt[2]);

    // ---------------- phase C: conv gate + out = x * gate * sig ----------------
    const uint2* gh = (const uint2*)gateh;
    int ntiles = (n + 255) >> 8;
    for (int tile = blockIdx.x; tile < ntiles; tile += GRID_BLKS) {
        int base = tile * 256;
        int i = base + t;
        __syncthreads();     // protect sgate reuse across tile iterations
        if (i < n) {
            float acc = 0.0f;
            #pragma unroll
            for (int k = 0; k < 27; ++k) {
                int j = conv_idx[(size_t)i * 27 + k];   // branchless clamp + mask
                int jc = j >= 0 ? j : 0;
                float msk = j >= 0 ? 1.0f : 0.0f;
                float2 zz2 = z[jc];
                acc += msk * (zz2.x * cw[2 * k] + zz2.y * cw[2 * k + 1]);
            }
            sgate[t] = sigmoidf_(acc);
        }
        __syncthreads();
        int npts = n - base; if (npts > 256) npts = 256;
        int tot = npts * 16;                            // float4s this tile owns
        for (int qq = t; qq < tot; qq += 256) {
            float s = sgate[qq >> 4];
            size_t Q = (size_t)base * 16 + qq;
            float4 v = xv[Q];
            uint2 g = gh[Q];
            float2 gl = unpack_h2(g.x);
            float2 gu = unpack_h2(g.y);
            out[Q] = make_float4(v.x * gl.x * s, v.y * gl.y * s,
                                 v.z * gu.x * s, v.w * gu.y * s);
        }
    }
}

extern "C" void kernel_launch(void* const* d_in, const int* in_sizes, int n_in,
                              void* d_out, int out_size, void* d_ws, size_t ws_size,
                              hipStream_t stream) {
    const float* x_F    = (const float*)d_in[0];
    const float* W1     = (const float*)d_in[1];
    const float* b1     = (const float*)d_in[2];
    const float* W2     = (const float*)d_in[3];
    const float* b2     = (const float*)d_in[4];
    const float* conv_w = (const float*)d_in[5];
    const int*   idx    = (const int*)d_in[6];
    const int*   cidx   = (const int*)d_in[7];
    int n = in_sizes[0] / CH;   // 100000

    char* ws = (char*)d_ws;
    size_t off = 0;
    uint2*  xb      = (uint2*)(ws + off);  off += (size_t)n * CH * 2;   // bf16 table
    uint4*  gateh   = (uint4*)(ws + off);  off += (size_t)n * CH * 2;   // f16 gate
    float2* rowstat = (float2*)(ws + off); off += (size_t)n * 8;
    float2* zz      = (float2*)(ws + off); off += (size_t)n * 8;
    unsigned int* barcnt = (unsigned int*)(ws + off); off += 64;

    // zero the barrier counters on-stream (capture-legal; replayed per iter)
    hipMemsetAsync(barcnt, 0, 64, stream);

    kFused<<<GRID_BLKS, 256, 0, stream>>>(
        (const float4*)x_F, W1, b1, W2, b2, conv_w,
        (const int2*)idx, (const int4*)idx, cidx,
        xb, gateh, rowstat, zz, (float4*)d_out, barcnt, n);
}

// Round 7
// 710.145 us; speedup vs baseline: 1.2459x; 1.2459x over previous
//
#include <hip/hip_runtime.h>
#include <hip/hip_fp16.h>
#include <math.h>

#define KNN 16
#define CH 64
#define HID 16
#define GRID_BLKS 768   // 3 blocks/CU on 256 CUs via __launch_bounds__(256,3);
                        // R5 ran this exact shape to completion -> co-residency
                        // of all 768 blocks is HW-validated. Barrier cannot
                        // starve.

__device__ __forceinline__ float sigmoidf_(float x) {
    return 1.0f / (1.0f + __expf(-x));
}

// pack two fp32 into bf16x2 (RNE), a in low16, b in high16
__device__ __forceinline__ unsigned int pack_bf2(float a, float b) {
    unsigned int ua = __float_as_uint(a), ub = __float_as_uint(b);
    ua = (ua + 0x7FFFu + ((ua >> 16) & 1u)) >> 16;
    ub = (ub + 0x7FFFu + ((ub >> 16) & 1u)) & 0xFFFF0000u;
    return ua | ub;
}

// unpack 4 packed bf16 -> float4
__device__ __forceinline__ float4 bf4_to_f4(unsigned int lo, unsigned int hi) {
    float4 r;
    r.x = __uint_as_float(lo << 16);
    r.y = __uint_as_float(lo & 0xFFFF0000u);
    r.z = __uint_as_float(hi << 16);
    r.w = __uint_as_float(hi & 0xFFFF0000u);
    return r;
}

// f16 pack/unpack for the gate (gate in (0,1): f16 rel err < 2^-11)
__device__ __forceinline__ unsigned int pack_h2(float a, float b) {
    __half2 h = __floats2half2_rn(a, b);
    return *(unsigned int*)&h;
}
__device__ __forceinline__ float2 unpack_h2(unsigned int u) {
    __half2 h;
    *(unsigned int*)&h = u;
    return __half22float2(h);
}

// R7 barrier. History: R5 (per-thread __threadfence + acquire spin-load)
// worked but was a fence storm -> 884us, VALU 4%. R6 (relaxed fetch_add(0)
// spin) HUNG: LLVM demotes "atomicrmw add 0" to an atomic LOAD, and a
// relaxed load is served from the spinner's LOCAL non-coherent XCD L2 ->
// stale counter forever. Fix: 64-bit counter; arrivals add 1 (low 32b),
// polls add 1<<32 (NON-ZERO -> stays a genuine RMW at the device coherence
// point; returned old value's low 32b is the authoritative arrival count;
// relaxed -> no cache op per poll). Exactly ONE wbl2 (release) and ONE inv
// (acquire) per block per barrier, thread 0 only. __syncthreads() before
// arrival: compiler emits s_waitcnt vmcnt(0) first, so all block stores are
// committed to L2 before the wbl2 flushes them to fabric. Spin is bounded:
// worst case = wrong answer + failed test, never a dead container.
__device__ __forceinline__ void grid_barrier(unsigned long long* cnt) {
    __syncthreads();
    if (threadIdx.x == 0) {
        __builtin_amdgcn_fence(__ATOMIC_RELEASE, "agent");   // one buffer_wbl2
        unsigned long long v = __hip_atomic_fetch_add(
            cnt, 1ull, __ATOMIC_RELAXED, __HIP_MEMORY_SCOPE_AGENT);
        if ((v & 0xFFFFFFFFull) + 1ull < (unsigned long long)GRID_BLKS) {
            int guard = 0;
            do {
                __builtin_amdgcn_s_sleep(8);                 // ~213ns/poll
                v = __hip_atomic_fetch_add(
                    cnt, 1ull << 32, __ATOMIC_RELAXED, __HIP_MEMORY_SCOPE_AGENT);
            } while ((v & 0xFFFFFFFFull) < (unsigned long long)GRID_BLKS
                     && ++guard < (1 << 22));
        }
        __builtin_amdgcn_fence(__ATOMIC_ACQUIRE, "agent");   // one buffer_inv
    }
    __syncthreads();
}

// R7: whole pipeline in ONE persistent kernel (kills 3 launch gaps of the
// 171us 4-kernel pipeline where kA is only 60us and is pinned at its
// gather-fetch floor). Phase bodies are the R5-proven ones (absmax 0.0156):
// fused phase A (gathers + MLP + fp32 own rows + rowstat; R3 proved
// splitting costs bandwidth 1.98->1.70 TB/s), f16 gate store (12.8MB)
// instead of fp32 outse (25.6MB), phase C reconstructs out = x*gate*sig.
// No nt hints (R2: bypass L3, regress).
__global__ __launch_bounds__(256, 3) void kFused(
        const float4* __restrict__ xv,
        const float* __restrict__ W1, const float* __restrict__ b1,
        const float* __restrict__ W2, const float* __restrict__ b2,
        const float* __restrict__ conv_w,
        const int2* __restrict__ idx2, const int4* __restrict__ idxv,
        const int* __restrict__ conv_idx,
        uint2* xb, uint4* gateh, float2* rowstat, float2* z,
        float4* out, unsigned long long* barcnt, int n) {
    __shared__ float4 w1a[128];   // w1a[h*8+s] = W1[(8s+0..3)][h]
    __shared__ float4 w1b[128];   // w1b[h*8+s] = W1[(8s+4..7)][h]
    __shared__ float4 w2q[256];   // float4 copy of W2 (16x64 row-major)
    __shared__ float cw[54];
    __shared__ float sgate[128];
    int t = threadIdx.x;

    // stage all LDS-resident params once
    if (t < 128) {
        int h = t >> 3, s = t & 7;
        float4 a, b;
        a.x = W1[(8 * s + 0) * HID + h];
        a.y = W1[(8 * s + 1) * HID + h];
        a.z = W1[(8 * s + 2) * HID + h];
        a.w = W1[(8 * s + 3) * HID + h];
        b.x = W1[(8 * s + 4) * HID + h];
        b.y = W1[(8 * s + 5) * HID + h];
        b.z = W1[(8 * s + 6) * HID + h];
        b.w = W1[(8 * s + 7) * HID + h];
        w1a[t] = a;
        w1b[t] = b;
    }
    w2q[t] = ((const float4*)W2)[t];
    if (t < 54) cw[t] = conv_w[t];
    __syncthreads();

    // ---------------- phase X: bf16 gather table ----------------
    int n16 = n * 16;
    for (int i = blockIdx.x * 256 + t; i < n16; i += GRID_BLKS * 256) {
        float4 v = xv[i];
        uint2 r;
        r.x = pack_bf2(v.x, v.y);
        r.y = pack_bf2(v.z, v.w);
        xb[i] = r;
    }
    grid_barrier(&barcnt[0]);

    // ---------------- phase A: gathers + MLP -> gate + rowstat ----------------
    const uint4* xb4 = (const uint4*)xb;
    int sub = t & 7;
    float b1a = b1[sub], b1b = b1[sub + 8];
    float4 bq0 = ((const float4*)b2)[2 * sub];
    float4 bq1 = ((const float4*)b2)[2 * sub + 1];
    for (int p0 = blockIdx.x * 32; p0 < n; p0 += GRID_BLKS * 32) {
        int p = p0 + (t >> 3);
        if (p < n) {   // uniform across each 8-lane group
            int2 jp = idx2[(size_t)p * 8 + sub];
            int jA[8], jB[8];
            #pragma unroll
            for (int s = 0; s < 8; ++s) {
                jA[s] = __shfl(jp.x, s, 8);
                jB[s] = __shfl(jp.y, s, 8);
            }

            // batch-issue all 16 gathers + own fp32 rows, pin with sched_barrier
            uint4 va[8], vb[8];
            #pragma unroll
            for (int s = 0; s < 8; ++s) va[s] = xb4[(size_t)jA[s] * 8 + sub];
            #pragma unroll
            for (int s = 0; s < 8; ++s) vb[s] = xb4[(size_t)jB[s] * 8 + sub];
            float4 own0 = xv[(size_t)p * 16 + 2 * sub];
            float4 own1 = xv[(size_t)p * 16 + 2 * sub + 1];
            __builtin_amdgcn_sched_barrier(0);

            float4 sumLo, sumHi, mxLo, mxHi;
            {
                float4 lo = bf4_to_f4(va[0].x, va[0].y);
                float4 hi = bf4_to_f4(va[0].z, va[0].w);
                sumLo = lo; mxLo = lo; sumHi = hi; mxHi = hi;
            }
            #pragma unroll
            for (int s = 1; s < 8; ++s) {
                float4 lo = bf4_to_f4(va[s].x, va[s].y);
                float4 hi = bf4_to_f4(va[s].z, va[s].w);
                sumLo.x += lo.x; sumLo.y += lo.y; sumLo.z += lo.z; sumLo.w += lo.w;
                sumHi.x += hi.x; sumHi.y += hi.y; sumHi.z += hi.z; sumHi.w += hi.w;
                mxLo.x = fmaxf(mxLo.x, lo.x); mxLo.y = fmaxf(mxLo.y, lo.y);
                mxLo.z = fmaxf(mxLo.z, lo.z); mxLo.w = fmaxf(mxLo.w, lo.w);
                mxHi.x = fmaxf(mxHi.x, hi.x); mxHi.y = fmaxf(mxHi.y, hi.y);
                mxHi.z = fmaxf(mxHi.z, hi.z); mxHi.w = fmaxf(mxHi.w, hi.w);
            }
            #pragma unroll
            for (int s = 0; s < 8; ++s) {
                float4 lo = bf4_to_f4(vb[s].x, vb[s].y);
                float4 hi = bf4_to_f4(vb[s].z, vb[s].w);
                sumLo.x += lo.x; sumLo.y += lo.y; sumLo.z += lo.z; sumLo.w += lo.w;
                sumHi.x += hi.x; sumHi.y += hi.y; sumHi.z += hi.z; sumHi.w += hi.w;
                mxLo.x = fmaxf(mxLo.x, lo.x); mxLo.y = fmaxf(mxLo.y, lo.y);
                mxLo.z = fmaxf(mxLo.z, lo.z); mxLo.w = fmaxf(mxLo.w, lo.w);
                mxHi.x = fmaxf(mxHi.x, hi.x); mxHi.y = fmaxf(mxHi.y, hi.y);
                mxHi.z = fmaxf(mxHi.z, hi.z); mxHi.w = fmaxf(mxHi.w, hi.w);
            }
            const float inv_k = 1.0f / KNN;
            float4 meLo = {sumLo.x * inv_k, sumLo.y * inv_k, sumLo.z * inv_k, sumLo.w * inv_k};
            float4 meHi = {sumHi.x * inv_k, sumHi.y * inv_k, sumHi.z * inv_k, sumHi.w * inv_k};

            float Hm_a, Hm_b, Hx_a, Hx_b;
            {
                float A[8], B[8];
                #pragma unroll
                for (int h = 0; h < 8; ++h) {
                    float4 wa = w1a[h * 8 + sub], wb = w1b[h * 8 + sub];
                    A[h] = meLo.x * wa.x + meLo.y * wa.y + meLo.z * wa.z + meLo.w * wa.w
                         + meHi.x * wb.x + meHi.y * wb.y + meHi.z * wb.z + meHi.w * wb.w;
                    float4 wa2 = w1a[(h + 8) * 8 + sub], wb2 = w1b[(h + 8) * 8 + sub];
                    B[h] = meLo.x * wa2.x + meLo.y * wa2.y + meLo.z * wa2.z + meLo.w * wa2.w
                         + meHi.x * wb2.x + meHi.y * wb2.y + meHi.z * wb2.z + meHi.w * wb2.w;
                }
                #pragma unroll
                for (int m = 4; m >= 1; m >>= 1) {
                    bool hi = (sub & m) != 0;
                    #pragma unroll
                    for (int i = 0; i < m; ++i) {
                        float sA = hi ? A[i] : A[i + m], kA_ = hi ? A[i + m] : A[i];
                        A[i] = kA_ + __shfl_xor(sA, m);
                        float sB = hi ? B[i] : B[i + m], kB_ = hi ? B[i + m] : B[i];
                        B[i] = kB_ + __shfl_xor(sB, m);
                    }
                }
                Hm_a = A[0]; Hm_b = B[0];
            }
            {
                float A[8], B[8];
                #pragma unroll
                for (int h = 0; h < 8; ++h) {
                    float4 wa = w1a[h * 8 + sub], wb = w1b[h * 8 + sub];
                    A[h] = mxLo.x * wa.x + mxLo.y * wa.y + mxLo.z * wa.z + mxLo.w * wa.w
                         + mxHi.x * wb.x + mxHi.y * wb.y + mxHi.z * wb.z + mxHi.w * wb.w;
                    float4 wa2 = w1a[(h + 8) * 8 + sub], wb2 = w1b[(h + 8) * 8 + sub];
                    B[h] = mxLo.x * wa2.x + mxLo.y * wa2.y + mxLo.z * wa2.z + mxLo.w * wa2.w
                         + mxHi.x * wb2.x + mxHi.y * wb2.y + mxHi.z * wb2.z + mxHi.w * wb2.w;
                }
                #pragma unroll
                for (int m = 4; m >= 1; m >>= 1) {
                    bool hi = (sub & m) != 0;
                    #pragma unroll
                    for (int i = 0; i < m; ++i) {
                        float sA = hi ? A[i] : A[i + m], kA_ = hi ? A[i + m] : A[i];
                        A[i] = kA_ + __shfl_xor(sA, m);
                        float sB = hi ? B[i] : B[i + m], kB_ = hi ? B[i + m] : B[i];
                        B[i] = kB_ + __shfl_xor(sB, m);
                    }
                }
                Hx_a = A[0]; Hx_b = B[0];
            }
            float H_a = fmaxf(Hm_a + b1a, 0.0f) + fmaxf(Hx_a + b1a, 0.0f);
            float H_b = fmaxf(Hm_b + b1b, 0.0f) + fmaxf(Hx_b + b1b, 0.0f);

            float4 a0 = {0.f, 0.f, 0.f, 0.f}, a1 = {0.f, 0.f, 0.f, 0.f};
            #pragma unroll
            for (int h = 0; h < 8; ++h) {
                float Hh = __shfl(H_a, h, 8);
                float4 w0 = w2q[h * 16 + 2 * sub], w1v = w2q[h * 16 + 2 * sub + 1];
                a0.x += Hh * w0.x; a0.y += Hh * w0.y; a0.z += Hh * w0.z; a0.w += Hh * w0.w;
                a1.x += Hh * w1v.x; a1.y += Hh * w1v.y; a1.z += Hh * w1v.z; a1.w += Hh * w1v.w;
            }
            #pragma unroll
            for (int h = 0; h < 8; ++h) {
                float Hh = __shfl(H_b, h, 8);
                float4 w0 = w2q[(h + 8) * 16 + 2 * sub], w1v = w2q[(h + 8) * 16 + 2 * sub + 1];
                a0.x += Hh * w0.x; a0.y += Hh * w0.y; a0.z += Hh * w0.z; a0.w += Hh * w0.w;
                a1.x += Hh * w1v.x; a1.y += Hh * w1v.y; a1.z += Hh * w1v.z; a1.w += Hh * w1v.w;
            }

            float s0 = sigmoidf_(a0.x + 2.0f * bq0.x);
            float s1 = sigmoidf_(a0.y + 2.0f * bq0.y);
            float s2 = sigmoidf_(a0.z + 2.0f * bq0.z);
            float s3 = sigmoidf_(a0.w + 2.0f * bq0.w);
            float s4 = sigmoidf_(a1.x + 2.0f * bq1.x);
            float s5 = sigmoidf_(a1.y + 2.0f * bq1.y);
            float s6 = sigmoidf_(a1.z + 2.0f * bq1.z);
            float s7 = sigmoidf_(a1.w + 2.0f * bq1.w);
            uint4 gv;
            gv.x = pack_h2(s0, s1);
            gv.y = pack_h2(s2, s3);
            gv.z = pack_h2(s4, s5);
            gv.w = pack_h2(s6, s7);
            gateh[(size_t)p * 8 + sub] = gv;

            // rowstat from fp32 own row * gate (exact outse values)
            float o0 = own0.x * s0, o1 = own0.y * s1;
            float o2 = own0.z * s2, o3 = own0.w * s3;
            float o4 = own1.x * s4, o5 = own1.y * s5;
            float o6 = own1.z * s6, o7 = own1.w * s7;
            float sm = (o0 + o1) + (o2 + o3) + ((o4 + o5) + (o6 + o7));
            float sx = fmaxf(fmaxf(fmaxf(o0, o1), fmaxf(o2, o3)),
                             fmaxf(fmaxf(o4, o5), fmaxf(o6, o7)));
            #pragma unroll
            for (int m = 4; m >= 1; m >>= 1) {
                sm += __shfl_xor(sm, m);
                sx = fmaxf(sx, __shfl_xor(sx, m));
            }
            if (sub == 0) rowstat[p] = make_float2(sm * (1.0f / 64.0f), sx);
        }
    }
    grid_barrier(&barcnt[32]);   // 256B-padded counters: no false sharing

    // ---------------- phase B: z = (mean_k rowmean, max_k rowmax) ----------------
    for (int q = blockIdx.x * 256 + t; q < 2 * n; q += GRID_BLKS * 256) {
        int i = q >> 1, half = q & 1;
        int4 a = idxv[(size_t)i * 4 + half * 2];
        int4 b = idxv[(size_t)i * 4 + half * 2 + 1];
        float2 s0 = rowstat[a.x], s1 = rowstat[a.y], s2 = rowstat[a.z], s3 = rowstat[a.w];
        float2 s4 = rowstat[b.x], s5 = rowstat[b.y], s6 = rowstat[b.z], s7 = rowstat[b.w];
        float zm = (s0.x + s1.x) + (s2.x + s3.x) + ((s4.x + s5.x) + (s6.x + s7.x));
        float zx = fmaxf(fmaxf(fmaxf(s0.y, s1.y), fmaxf(s2.y, s3.y)),
                         fmaxf(fmaxf(s4.y, s5.y), fmaxf(s6.y, s7.y)));
        zm += __shfl_xor(zm, 1);
        zx = fmaxf(zx, __shfl_xor(zx, 1));
        if (half == 0) z[i] = make_float2(zm * (1.0f / 16.0f), zx);
    }
    grid_barrier(&barcnt[64]);

    // ---------------- phase C: conv gate + out = x * gate * sig ----------------
    // 128-point tiles: 782 tiles ~ 768 blocks (256-pt tiles would idle half
    // the grid in this latency-sensitive phase).
    const uint2* gh = (const uint2*)gateh;
    int ntilesC = (n + 127) >> 7;
    for (int tile = blockIdx.x; tile < ntilesC; tile += GRID_BLKS) {
        int base = tile * 128;
        __syncthreads();     // protect sgate reuse across tile iterations
        if (t < 128) {
            int i = base + t;
            if (i < n) {
                float acc = 0.0f;
                #pragma unroll
                for (int k = 0; k < 27; ++k) {
                    int j = conv_idx[(size_t)i * 27 + k];   // branchless clamp+mask
                    int jc = j >= 0 ? j : 0;
                    float msk = j >= 0 ? 1.0f : 0.0f;
                    float2 zz2 = z[jc];
                    acc += msk * (zz2.x * cw[2 * k] + zz2.y * cw[2 * k + 1]);
                }
                sgate[t] = sigmoidf_(acc);
            }
        }
        __syncthreads();
        int npts = n - base; if (npts > 128) npts = 128;
        int tot = npts * 16;                            // float4s this tile owns
        for (int qq = t; qq < tot; qq += 256) {
            float s = sgate[qq >> 4];
            size_t Q = (size_t)base * 16 + qq;
            float4 v = xv[Q];
            uint2 g = gh[Q];
            float2 gl = unpack_h2(g.x);
            float2 gu = unpack_h2(g.y);
            out[Q] = make_float4(v.x * gl.x * s, v.y * gl.y * s,
                                 v.z * gu.x * s, v.w * gu.y * s);
        }
    }
}

extern "C" void kernel_launch(void* const* d_in, const int* in_sizes, int n_in,
                              void* d_out, int out_size, void* d_ws, size_t ws_size,
                              hipStream_t stream) {
    const float* x_F    = (const float*)d_in[0];
    const float* W1     = (const float*)d_in[1];
    const float* b1     = (const float*)d_in[2];
    const float* W2     = (const float*)d_in[3];
    const float* b2     = (const float*)d_in[4];
    const float* conv_w = (const float*)d_in[5];
    const int*   idx    = (const int*)d_in[6];
    const int*   cidx   = (const int*)d_in[7];
    int n = in_sizes[0] / CH;   // 100000

    char* ws = (char*)d_ws;
    size_t off = 0;
    uint2*  xb      = (uint2*)(ws + off);  off += (size_t)n * CH * 2;   // bf16 table
    uint4*  gateh   = (uint4*)(ws + off);  off += (size_t)n * CH * 2;   // f16 gate
    float2* rowstat = (float2*)(ws + off); off += (size_t)n * 8;
    float2* zz      = (float2*)(ws + off); off += (size_t)n * 8;
    unsigned long long* barcnt = (unsigned long long*)(ws + off); off += 1024;

    // zero the 3 barrier counters on-stream (capture-legal; replayed per iter)
    hipMemsetAsync(barcnt, 0, 1024, stream);

    kFused<<<GRID_BLKS, 256, 0, stream>>>(
        (const float4*)x_F, W1, b1, W2, b2, conv_w,
        (const int2*)idx, (const int4*)idx, cidx,
        xb, gateh, rowstat, zz, (float4*)d_out, barcnt, n);
}

// Round 8
// 236.002 us; speedup vs baseline: 3.7490x; 3.0091x over previous
//
#include <hip/hip_runtime.h>
#include <math.h>

#define KNN 16
#define CH 64
#define HID 16
#define NEG_BIG (-3.402823466e+38f)

__device__ __forceinline__ float sigmoidf_(float x) {
    return 1.0f / (1.0f + __expf(-x));
}

// pack two fp32 into bf16x2 (RNE), a in low16, b in high16
__device__ __forceinline__ unsigned int pack_bf2(float a, float b) {
    unsigned int ua = __float_as_uint(a), ub = __float_as_uint(b);
    ua = (ua + 0x7FFFu + ((ua >> 16) & 1u)) >> 16;
    ub = (ub + 0x7FFFu + ((ub >> 16) & 1u)) & 0xFFFF0000u;
    return ua | ub;
}

// unpack 4 packed bf16 -> float4
__device__ __forceinline__ float4 bf4_to_f4(unsigned int lo, unsigned int hi) {
    float4 r;
    r.x = __uint_as_float(lo << 16);
    r.y = __uint_as_float(lo & 0xFFFF0000u);
    r.z = __uint_as_float(hi << 16);
    r.w = __uint_as_float(hi & 0xFFFF0000u);
    return r;
}

// paired fold-reduce across an 8-lane group: A[8],B[8] partials -> lane sub
// ends holding full sums A -> H[sub], B -> H[sub+8].
__device__ __forceinline__ void fold8_2(float A[8], float B[8], int sub) {
    #pragma unroll
    for (int m = 4; m >= 1; m >>= 1) {
        bool hi = (sub & m) != 0;
        #pragma unroll
        for (int i = 0; i < m; ++i) {
            float sA = hi ? A[i] : A[i + m], kA_ = hi ? A[i + m] : A[i];
            A[i] = kA_ + __shfl_xor(sA, m);
            float sB = hi ? B[i] : B[i + m], kB_ = hi ? B[i + m] : B[i];
            B[i] = kB_ + __shfl_xor(sB, m);
        }
    }
}

// Pre-pass: bf16 copy of x_F (halves gather lines + cache footprint for kA)
__global__ __launch_bounds__(256) void kX(const float4* __restrict__ xv,
                                          uint2* __restrict__ xb, int n16) {
    int i = blockIdx.x * 256 + threadIdx.x;
    if (i >= n16) return;
    float4 v = xv[i];
    uint2 r;
    r.x = pack_bf2(v.x, v.y);
    r.y = pack_bf2(v.z, v.w);
    xb[i] = r;
}

// Phase A: channel attention. 8 lanes per point (8 points/wave), lane owns 8
// channels (uint4 = 8 bf16, 16B). One bf16 row = 128B = one 8-lane slice ->
// gathers keep the proven dwordx4/1KB-per-inst shape at HALF the bytes.
// R8 status: kA is at its structural floor — fetch 119.4 MB (gather coverage
// floor ~88 MB + own fp32 rows 25.6 + idx 6.4) at 1.98 TB/s (measured random
// L2-miss ceiling), VALUBusy 50% (joint limit). R1/R2/R3/R5/R7 all failed to
// beat this shape: table-read own rows add gather misses (R1), nt hints
// bypass L3 (R2), splitting drops MLP (R3: 1.98->1.70 TB/s), persistent
// fusion drowns in barrier-poll fabric flood (R5/R7). launch_bounds(256,4):
// occupancy-cap hint only (VGPR 84 < 128 cap -> codegen unchanged).
__global__ __launch_bounds__(256, 4) void kA(const float4* __restrict__ xv,
        const uint4* __restrict__ xb4,
        const float* __restrict__ W1, const float* __restrict__ b1,
        const float* __restrict__ W2, const float* __restrict__ b2,
        const int2* __restrict__ idx2,
        float4* __restrict__ outse, float2* __restrict__ rowstat, int n) {
    __shared__ float4 w1a[128];   // w1a[h*8+s] = W1[(8s+0..3)][h]
    __shared__ float4 w1b[128];   // w1b[h*8+s] = W1[(8s+4..7)][h]
    __shared__ float4 w2q[256];   // float4 copy of W2 (16x64 row-major)
    int t = threadIdx.x;
    if (t < 128) {
        int h = t >> 3, s = t & 7;
        float4 a, b;
        a.x = W1[(8 * s + 0) * HID + h];
        a.y = W1[(8 * s + 1) * HID + h];
        a.z = W1[(8 * s + 2) * HID + h];
        a.w = W1[(8 * s + 3) * HID + h];
        b.x = W1[(8 * s + 4) * HID + h];
        b.y = W1[(8 * s + 5) * HID + h];
        b.z = W1[(8 * s + 6) * HID + h];
        b.w = W1[(8 * s + 7) * HID + h];
        w1a[t] = a;
        w1b[t] = b;
    }
    w2q[t] = ((const float4*)W2)[t];
    __syncthreads();

    int p = blockIdx.x * 32 + (t >> 3);
    int sub = t & 7;
    if (p >= n) return;

    // 16 neighbor indices live as int2 per lane; broadcast via width-8 shfl
    int2 jp = idx2[(size_t)p * 8 + sub];
    int jA[8], jB[8];
    #pragma unroll
    for (int s = 0; s < 8; ++s) {
        jA[s] = __shfl(jp.x, s, 8);
        jB[s] = __shfl(jp.y, s, 8);
    }

    // issue all 16 gathers + own-row/bias loads, then pin with sched_barrier
    // (serialized issue measured 0.7 TB/s vs ~2.0 TB/s batched)
    uint4 va[8], vb[8];
    #pragma unroll
    for (int s = 0; s < 8; ++s) va[s] = xb4[(size_t)jA[s] * 8 + sub];
    #pragma unroll
    for (int s = 0; s < 8; ++s) vb[s] = xb4[(size_t)jB[s] * 8 + sub];
    float4 own0 = xv[(size_t)p * 16 + 2 * sub];
    float4 own1 = xv[(size_t)p * 16 + 2 * sub + 1];
    float b1a = b1[sub], b1b = b1[sub + 8];
    float4 bq0 = ((const float4*)b2)[2 * sub];
    float4 bq1 = ((const float4*)b2)[2 * sub + 1];
    __builtin_amdgcn_sched_barrier(0);

    float4 sumLo, sumHi, mxLo, mxHi;
    {
        float4 lo = bf4_to_f4(va[0].x, va[0].y);
        float4 hi = bf4_to_f4(va[0].z, va[0].w);
        sumLo = lo; mxLo = lo; sumHi = hi; mxHi = hi;
    }
    #pragma unroll
    for (int s = 1; s < 8; ++s) {
        float4 lo = bf4_to_f4(va[s].x, va[s].y);
        float4 hi = bf4_to_f4(va[s].z, va[s].w);
        sumLo.x += lo.x; sumLo.y += lo.y; sumLo.z += lo.z; sumLo.w += lo.w;
        sumHi.x += hi.x; sumHi.y += hi.y; sumHi.z += hi.z; sumHi.w += hi.w;
        mxLo.x = fmaxf(mxLo.x, lo.x); mxLo.y = fmaxf(mxLo.y, lo.y);
        mxLo.z = fmaxf(mxLo.z, lo.z); mxLo.w = fmaxf(mxLo.w, lo.w);
        mxHi.x = fmaxf(mxHi.x, hi.x); mxHi.y = fmaxf(mxHi.y, hi.y);
        mxHi.z = fmaxf(mxHi.z, hi.z); mxHi.w = fmaxf(mxHi.w, hi.w);
    }
    #pragma unroll
    for (int s = 0; s < 8; ++s) {
        float4 lo = bf4_to_f4(vb[s].x, vb[s].y);
        float4 hi = bf4_to_f4(vb[s].z, vb[s].w);
        sumLo.x += lo.x; sumLo.y += lo.y; sumLo.z += lo.z; sumLo.w += lo.w;
        sumHi.x += hi.x; sumHi.y += hi.y; sumHi.z += hi.z; sumHi.w += hi.w;
        mxLo.x = fmaxf(mxLo.x, lo.x); mxLo.y = fmaxf(mxLo.y, lo.y);
        mxLo.z = fmaxf(mxLo.z, lo.z); mxLo.w = fmaxf(mxLo.w, lo.w);
        mxHi.x = fmaxf(mxHi.x, hi.x); mxHi.y = fmaxf(mxHi.y, hi.y);
        mxHi.z = fmaxf(mxHi.z, hi.z); mxHi.w = fmaxf(mxHi.w, hi.w);
    }
    const float inv_k = 1.0f / KNN;
    float4 meLo = {sumLo.x * inv_k, sumLo.y * inv_k, sumLo.z * inv_k, sumLo.w * inv_k};
    float4 meHi = {sumHi.x * inv_k, sumHi.y * inv_k, sumHi.z * inv_k, sumHi.w * inv_k};

    // layer 1: mean path then max path; fold over the 8-lane group
    float Hm_a, Hm_b, Hx_a, Hx_b;
    {
        float A[8], B[8];
        #pragma unroll
        for (int h = 0; h < 8; ++h) {
            float4 wa = w1a[h * 8 + sub], wb = w1b[h * 8 + sub];
            A[h] = meLo.x * wa.x + meLo.y * wa.y + meLo.z * wa.z + meLo.w * wa.w
                 + meHi.x * wb.x + meHi.y * wb.y + meHi.z * wb.z + meHi.w * wb.w;
            float4 wa2 = w1a[(h + 8) * 8 + sub], wb2 = w1b[(h + 8) * 8 + sub];
            B[h] = meLo.x * wa2.x + meLo.y * wa2.y + meLo.z * wa2.z + meLo.w * wa2.w
                 + meHi.x * wb2.x + meHi.y * wb2.y + meHi.z * wb2.z + meHi.w * wb2.w;
        }
        fold8_2(A, B, sub);
        Hm_a = A[0]; Hm_b = B[0];
    }
    {
        float A[8], B[8];
        #pragma unroll
        for (int h = 0; h < 8; ++h) {
            float4 wa = w1a[h * 8 + sub], wb = w1b[h * 8 + sub];
            A[h] = mxLo.x * wa.x + mxLo.y * wa.y + mxLo.z * wa.z + mxLo.w * wa.w
                 + mxHi.x * wb.x + mxHi.y * wb.y + mxHi.z * wb.z + mxHi.w * wb.w;
            float4 wa2 = w1a[(h + 8) * 8 + sub], wb2 = w1b[(h + 8) * 8 + sub];
            B[h] = mxLo.x * wa2.x + mxLo.y * wa2.y + mxLo.z * wa2.z + mxLo.w * wa2.w
                 + mxHi.x * wb2.x + mxHi.y * wb2.y + mxHi.z * wb2.z + mxHi.w * wb2.w;
        }
        fold8_2(A, B, sub);
        Hx_a = A[0]; Hx_b = B[0];
    }
    float H_a = fmaxf(Hm_a + b1a, 0.0f) + fmaxf(Hx_a + b1a, 0.0f);
    float H_b = fmaxf(Hm_b + b1b, 0.0f) + fmaxf(Hx_b + b1b, 0.0f);

    // layer 2: own 8 channels = sum_h H[h] * W2[h][c]
    float4 a0 = {0.f, 0.f, 0.f, 0.f}, a1 = {0.f, 0.f, 0.f, 0.f};
    #pragma unroll
    for (int h = 0; h < 8; ++h) {
        float Hh = __shfl(H_a, h, 8);
        float4 w0 = w2q[h * 16 + 2 * sub], w1v = w2q[h * 16 + 2 * sub + 1];
        a0.x += Hh * w0.x; a0.y += Hh * w0.y; a0.z += Hh * w0.z; a0.w += Hh * w0.w;
        a1.x += Hh * w1v.x; a1.y += Hh * w1v.y; a1.z += Hh * w1v.z; a1.w += Hh * w1v.w;
    }
    #pragma unroll
    for (int h = 0; h < 8; ++h) {
        float Hh = __shfl(H_b, h, 8);
        float4 w0 = w2q[(h + 8) * 16 + 2 * sub], w1v = w2q[(h + 8) * 16 + 2 * sub + 1];
        a0.x += Hh * w0.x; a0.y += Hh * w0.y; a0.z += Hh * w0.z; a0.w += Hh * w0.w;
        a1.x += Hh * w1v.x; a1.y += Hh * w1v.y; a1.z += Hh * w1v.z; a1.w += Hh * w1v.w;
    }
    float4 o0, o1;
    o0.x = own0.x * sigmoidf_(a0.x + 2.0f * bq0.x);
    o0.y = own0.y * sigmoidf_(a0.y + 2.0f * bq0.y);
    o0.z = own0.z * sigmoidf_(a0.z + 2.0f * bq0.z);
    o0.w = own0.w * sigmoidf_(a0.w + 2.0f * bq0.w);
    o1.x = own1.x * sigmoidf_(a1.x + 2.0f * bq1.x);
    o1.y = own1.y * sigmoidf_(a1.y + 2.0f * bq1.y);
    o1.z = own1.z * sigmoidf_(a1.z + 2.0f * bq1.z);
    o1.w = own1.w * sigmoidf_(a1.w + 2.0f * bq1.w);
    outse[(size_t)p * 16 + 2 * sub] = o0;
    outse[(size_t)p * 16 + 2 * sub + 1] = o1;

    // per-row stats for phase B (8B/neighbor there instead of 128B)
    float sm = (o0.x + o0.y + o0.z + o0.w) + (o1.x + o1.y + o1.z + o1.w);
    float sx = fmaxf(fmaxf(fmaxf(o0.x, o0.y), fmaxf(o0.z, o0.w)),
                     fmaxf(fmaxf(o1.x, o1.y), fmaxf(o1.z, o1.w)));
    #pragma unroll
    for (int m = 4; m >= 1; m >>= 1) {
        sm += __shfl_xor(sm, m);
        sx = fmaxf(sx, __shfl_xor(sx, m));
    }
    if (sub == 0) rowstat[p] = make_float2(sm * (1.0f / 64.0f), sx);
}

// Phase B: z[n] = (mean_k rowmean, max_k rowmax). 2 lanes per point.
__global__ __launch_bounds__(256) void kB(const int4* __restrict__ idxv,
        const float2* __restrict__ rowstat, float2* __restrict__ z, int n) {
    int t = blockIdx.x * 256 + threadIdx.x;
    int i = t >> 1, half = t & 1;
    if (i >= n) return;
    int4 a = idxv[(size_t)i * 4 + half * 2];
    int4 b = idxv[(size_t)i * 4 + half * 2 + 1];
    float2 s0 = rowstat[a.x], s1 = rowstat[a.y], s2 = rowstat[a.z], s3 = rowstat[a.w];
    float2 s4 = rowstat[b.x], s5 = rowstat[b.y], s6 = rowstat[b.z], s7 = rowstat[b.w];
    float zm = (s0.x + s1.x) + (s2.x + s3.x) + ((s4.x + s5.x) + (s6.x + s7.x));
    float zx = fmaxf(fmaxf(fmaxf(s0.y, s1.y), fmaxf(s2.y, s3.y)),
                     fmaxf(fmaxf(s4.y, s5.y), fmaxf(s6.y, s7.y)));
    zm += __shfl_xor(zm, 1);
    zx = fmaxf(zx, __shfl_xor(zx, 1));
    if (half == 0) z[i] = make_float2(zm * (1.0f / 16.0f), zx);
}

// Phase C (fused conv + scale): sig per point via LDS, then out = outse * sig.
// R8: retiled 256 -> 128 points/block (391 -> 782 blocks). The conv phase is
// 27 serial masked z-gathers per thread (latency-bound); at 391 blocks the
// GPU had only ~1.5 blocks/CU of TLP to hide that latency. 128-pt tiles
// double block-level parallelism; the scale loop still uses all 256 threads
// (2048 float4s / 256 = 8 iters).
__global__ __launch_bounds__(256) void kC(const int* __restrict__ conv_idx,
        const float* __restrict__ conv_w, const float2* __restrict__ z,
        const float4* __restrict__ outse, float4* __restrict__ out, int n) {
    __shared__ float cw[54];
    __shared__ float sgate[128];
    if (threadIdx.x < 54) cw[threadIdx.x] = conv_w[threadIdx.x];
    __syncthreads();
    int base = blockIdx.x * 128;
    int t = threadIdx.x;
    if (t < 128) {
        int i = base + t;
        if (i < n) {
            float acc = 0.0f;
            #pragma unroll
            for (int k = 0; k < 27; ++k) {
                int j = conv_idx[(size_t)i * 27 + k];   // branchless clamp + mask
                int jc = j >= 0 ? j : 0;
                float msk = j >= 0 ? 1.0f : 0.0f;
                float2 zz = z[jc];
                acc += msk * (zz.x * cw[2 * k] + zz.y * cw[2 * k + 1]);
            }
            sgate[t] = sigmoidf_(acc);
        }
    }
    __syncthreads();
    int npts = n - base; if (npts > 128) npts = 128;
    int tot = npts * 16;                            // float4s this block owns
    for (int q = t; q < tot; q += 256) {
        float s = sgate[q >> 4];
        float4 v = outse[(size_t)base * 16 + q];
        out[(size_t)base * 16 + q] = make_float4(v.x * s, v.y * s, v.z * s, v.w * s);
    }
}

extern "C" void kernel_launch(void* const* d_in, const int* in_sizes, int n_in,
                              void* d_out, int out_size, void* d_ws, size_t ws_size,
                              hipStream_t stream) {
    const float* x_F    = (const float*)d_in[0];
    const float* W1     = (const float*)d_in[1];
    const float* b1     = (const float*)d_in[2];
    const float* W2     = (const float*)d_in[3];
    const float* b2     = (const float*)d_in[4];
    const float* conv_w = (const float*)d_in[5];
    const int*   idx    = (const int*)d_in[6];
    const int*   cidx   = (const int*)d_in[7];
    int n = in_sizes[0] / CH;   // 100000

    char* ws = (char*)d_ws;
    size_t off = 0;
    uint2*  xb      = (uint2*)(ws + off);  off += (size_t)n * CH * 2;   // bf16 table
    float*  outse   = (float*)(ws + off);  off += (size_t)n * CH * 4;
    float2* rowstat = (float2*)(ws + off); off += (size_t)n * 8;
    float2* zz      = (float2*)(ws + off); off += (size_t)n * 8;

    int n16 = n * 16;
    kX<<<(n16 + 255) / 256, 256, 0, stream>>>((const float4*)x_F, xb, n16);
    int blkA = (n + 31) / 32;
    kA<<<blkA, 256, 0, stream>>>((const float4*)x_F, (const uint4*)xb,
                                 W1, b1, W2, b2, (const int2*)idx,
                                 (float4*)outse, rowstat, n);
    int blkB = (2 * n + 255) / 256;
    kB<<<blkB, 256, 0, stream>>>((const int4*)idx, rowstat, zz, n);
    int blkP = (n + 127) / 128;
    kC<<<blkP, 256, 0, stream>>>(cidx, conv_w, zz, (const float4*)outse,
                                 (float4*)d_out, n);
}

// Round 9
// 172.066 us; speedup vs baseline: 5.1421x; 1.3716x over previous
//
#include <hip/hip_runtime.h>
#include <math.h>

#define KNN 16
#define CH 64
#define HID 16
#define NEG_BIG (-3.402823466e+38f)

__device__ __forceinline__ float sigmoidf_(float x) {
    return 1.0f / (1.0f + __expf(-x));
}

// pack two fp32 into bf16x2 (RNE), a in low16, b in high16
__device__ __forceinline__ unsigned int pack_bf2(float a, float b) {
    unsigned int ua = __float_as_uint(a), ub = __float_as_uint(b);
    ua = (ua + 0x7FFFu + ((ua >> 16) & 1u)) >> 16;
    ub = (ub + 0x7FFFu + ((ub >> 16) & 1u)) & 0xFFFF0000u;
    return ua | ub;
}

// unpack 4 packed bf16 -> float4
__device__ __forceinline__ float4 bf4_to_f4(unsigned int lo, unsigned int hi) {
    float4 r;
    r.x = __uint_as_float(lo << 16);
    r.y = __uint_as_float(lo & 0xFFFF0000u);
    r.z = __uint_as_float(hi << 16);
    r.w = __uint_as_float(hi & 0xFFFF0000u);
    return r;
}

// paired fold-reduce across an 8-lane group: A[8],B[8] partials -> lane sub
// ends holding full sums A -> H[sub], B -> H[sub+8].
__device__ __forceinline__ void fold8_2(float A[8], float B[8], int sub) {
    #pragma unroll
    for (int m = 4; m >= 1; m >>= 1) {
        bool hi = (sub & m) != 0;
        #pragma unroll
        for (int i = 0; i < m; ++i) {
            float sA = hi ? A[i] : A[i + m], kA_ = hi ? A[i + m] : A[i];
            A[i] = kA_ + __shfl_xor(sA, m);
            float sB = hi ? B[i] : B[i + m], kB_ = hi ? B[i + m] : B[i];
            B[i] = kB_ + __shfl_xor(sB, m);
        }
    }
}

// Pre-pass: bf16 copy of x_F (halves gather lines + cache footprint for kA)
__global__ __launch_bounds__(256) void kX(const float4* __restrict__ xv,
                                          uint2* __restrict__ xb, int n16) {
    int i = blockIdx.x * 256 + threadIdx.x;
    if (i >= n16) return;
    float4 v = xv[i];
    uint2 r;
    r.x = pack_bf2(v.x, v.y);
    r.y = pack_bf2(v.z, v.w);
    xb[i] = r;
}

// Phase A: channel attention. 8 lanes per point (8 points/wave), lane owns 8
// channels (uint4 = 8 bf16, 16B). One bf16 row = 128B = one 8-lane slice ->
// gathers keep the proven dwordx4/1KB-per-inst shape at HALF the bytes.
// launch_bounds(256,3) is LOAD-BEARING: R8 measured that (256,4) shrinks the
// allocator to 64 VGPR, which cannot hold the 16xuint4 batched gather payload
// -> scratch spills (+190MB WRITE, +102MB FETCH, kA 60->127us). DO NOT TOUCH.
// kA status: structural floor — fetch 119.4MB (gather coverage floor ~88MB,
// information-theoretic: 8 XCDs x 12.8MB x (1-e^-2) + own fp32 25.6 + idx
// 6.4) at 1.98 TB/s measured random-miss ceiling, VALUBusy 50% (joint limit).
// Refuted alternatives: own-rows-from-table adds gather misses (R1), nt hints
// bypass L3 (R2), phase split drops MLP overlap 1.98->1.70 TB/s (R3),
// persistent-kernel fusion drowns in cross-XCD barrier cost (R5/R7), fp8
// table would blow the absmax budget (margin is only 3.3x at bf16).
__global__ __launch_bounds__(256, 3) void kA(const float4* __restrict__ xv,
        const uint4* __restrict__ xb4,
        const float* __restrict__ W1, const float* __restrict__ b1,
        const float* __restrict__ W2, const float* __restrict__ b2,
        const int2* __restrict__ idx2,
        float4* __restrict__ outse, float2* __restrict__ rowstat, int n) {
    __shared__ float4 w1a[128];   // w1a[h*8+s] = W1[(8s+0..3)][h]
    __shared__ float4 w1b[128];   // w1b[h*8+s] = W1[(8s+4..7)][h]
    __shared__ float4 w2q[256];   // float4 copy of W2 (16x64 row-major)
    int t = threadIdx.x;
    if (t < 128) {
        int h = t >> 3, s = t & 7;
        float4 a, b;
        a.x = W1[(8 * s + 0) * HID + h];
        a.y = W1[(8 * s + 1) * HID + h];
        a.z = W1[(8 * s + 2) * HID + h];
        a.w = W1[(8 * s + 3) * HID + h];
        b.x = W1[(8 * s + 4) * HID + h];
        b.y = W1[(8 * s + 5) * HID + h];
        b.z = W1[(8 * s + 6) * HID + h];
        b.w = W1[(8 * s + 7) * HID + h];
        w1a[t] = a;
        w1b[t] = b;
    }
    w2q[t] = ((const float4*)W2)[t];
    __syncthreads();

    int p = blockIdx.x * 32 + (t >> 3);
    int sub = t & 7;
    if (p >= n) return;

    // 16 neighbor indices live as int2 per lane; broadcast via width-8 shfl
    int2 jp = idx2[(size_t)p * 8 + sub];
    int jA[8], jB[8];
    #pragma unroll
    for (int s = 0; s < 8; ++s) {
        jA[s] = __shfl(jp.x, s, 8);
        jB[s] = __shfl(jp.y, s, 8);
    }

    // issue all 16 gathers + own-row/bias loads, then pin with sched_barrier
    // (serialized issue measured 0.7 TB/s vs ~2.0 TB/s batched)
    uint4 va[8], vb[8];
    #pragma unroll
    for (int s = 0; s < 8; ++s) va[s] = xb4[(size_t)jA[s] * 8 + sub];
    #pragma unroll
    for (int s = 0; s < 8; ++s) vb[s] = xb4[(size_t)jB[s] * 8 + sub];
    float4 own0 = xv[(size_t)p * 16 + 2 * sub];
    float4 own1 = xv[(size_t)p * 16 + 2 * sub + 1];
    float b1a = b1[sub], b1b = b1[sub + 8];
    float4 bq0 = ((const float4*)b2)[2 * sub];
    float4 bq1 = ((const float4*)b2)[2 * sub + 1];
    __builtin_amdgcn_sched_barrier(0);

    float4 sumLo, sumHi, mxLo, mxHi;
    {
        float4 lo = bf4_to_f4(va[0].x, va[0].y);
        float4 hi = bf4_to_f4(va[0].z, va[0].w);
        sumLo = lo; mxLo = lo; sumHi = hi; mxHi = hi;
    }
    #pragma unroll
    for (int s = 1; s < 8; ++s) {
        float4 lo = bf4_to_f4(va[s].x, va[s].y);
        float4 hi = bf4_to_f4(va[s].z, va[s].w);
        sumLo.x += lo.x; sumLo.y += lo.y; sumLo.z += lo.z; sumLo.w += lo.w;
        sumHi.x += hi.x; sumHi.y += hi.y; sumHi.z += hi.z; sumHi.w += hi.w;
        mxLo.x = fmaxf(mxLo.x, lo.x); mxLo.y = fmaxf(mxLo.y, lo.y);
        mxLo.z = fmaxf(mxLo.z, lo.z); mxLo.w = fmaxf(mxLo.w, lo.w);
        mxHi.x = fmaxf(mxHi.x, hi.x); mxHi.y = fmaxf(mxHi.y, hi.y);
        mxHi.z = fmaxf(mxHi.z, hi.z); mxHi.w = fmaxf(mxHi.w, hi.w);
    }
    #pragma unroll
    for (int s = 0; s < 8; ++s) {
        float4 lo = bf4_to_f4(vb[s].x, vb[s].y);
        float4 hi = bf4_to_f4(vb[s].z, vb[s].w);
        sumLo.x += lo.x; sumLo.y += lo.y; sumLo.z += lo.z; sumLo.w += lo.w;
        sumHi.x += hi.x; sumHi.y += hi.y; sumHi.z += hi.z; sumHi.w += hi.w;
        mxLo.x = fmaxf(mxLo.x, lo.x); mxLo.y = fmaxf(mxLo.y, lo.y);
        mxLo.z = fmaxf(mxLo.z, lo.z); mxLo.w = fmaxf(mxLo.w, lo.w);
        mxHi.x = fmaxf(mxHi.x, hi.x); mxHi.y = fmaxf(mxHi.y, hi.y);
        mxHi.z = fmaxf(mxHi.z, hi.z); mxHi.w = fmaxf(mxHi.w, hi.w);
    }
    const float inv_k = 1.0f / KNN;
    float4 meLo = {sumLo.x * inv_k, sumLo.y * inv_k, sumLo.z * inv_k, sumLo.w * inv_k};
    float4 meHi = {sumHi.x * inv_k, sumHi.y * inv_k, sumHi.z * inv_k, sumHi.w * inv_k};

    // layer 1: mean path then max path; fold over the 8-lane group
    float Hm_a, Hm_b, Hx_a, Hx_b;
    {
        float A[8], B[8];
        #pragma unroll
        for (int h = 0; h < 8; ++h) {
            float4 wa = w1a[h * 8 + sub], wb = w1b[h * 8 + sub];
            A[h] = meLo.x * wa.x + meLo.y * wa.y + meLo.z * wa.z + meLo.w * wa.w
                 + meHi.x * wb.x + meHi.y * wb.y + meHi.z * wb.z + meHi.w * wb.w;
            float4 wa2 = w1a[(h + 8) * 8 + sub], wb2 = w1b[(h + 8) * 8 + sub];
            B[h] = meLo.x * wa2.x + meLo.y * wa2.y + meLo.z * wa2.z + meLo.w * wa2.w
                 + meHi.x * wb2.x + meHi.y * wb2.y + meHi.z * wb2.z + meHi.w * wb2.w;
        }
        fold8_2(A, B, sub);
        Hm_a = A[0]; Hm_b = B[0];
    }
    {
        float A[8], B[8];
        #pragma unroll
        for (int h = 0; h < 8; ++h) {
            float4 wa = w1a[h * 8 + sub], wb = w1b[h * 8 + sub];
            A[h] = mxLo.x * wa.x + mxLo.y * wa.y + mxLo.z * wa.z + mxLo.w * wa.w
                 + mxHi.x * wb.x + mxHi.y * wb.y + mxHi.z * wb.z + mxHi.w * wb.w;
            float4 wa2 = w1a[(h + 8) * 8 + sub], wb2 = w1b[(h + 8) * 8 + sub];
            B[h] = mxLo.x * wa2.x + mxLo.y * wa2.y + mxLo.z * wa2.z + mxLo.w * wa2.w
                 + mxHi.x * wb2.x + mxHi.y * wb2.y + mxHi.z * wb2.z + mxHi.w * wb2.w;
        }
        fold8_2(A, B, sub);
        Hx_a = A[0]; Hx_b = B[0];
    }
    float H_a = fmaxf(Hm_a + b1a, 0.0f) + fmaxf(Hx_a + b1a, 0.0f);
    float H_b = fmaxf(Hm_b + b1b, 0.0f) + fmaxf(Hx_b + b1b, 0.0f);

    // layer 2: own 8 channels = sum_h H[h] * W2[h][c]
    float4 a0 = {0.f, 0.f, 0.f, 0.f}, a1 = {0.f, 0.f, 0.f, 0.f};
    #pragma unroll
    for (int h = 0; h < 8; ++h) {
        float Hh = __shfl(H_a, h, 8);
        float4 w0 = w2q[h * 16 + 2 * sub], w1v = w2q[h * 16 + 2 * sub + 1];
        a0.x += Hh * w0.x; a0.y += Hh * w0.y; a0.z += Hh * w0.z; a0.w += Hh * w0.w;
        a1.x += Hh * w1v.x; a1.y += Hh * w1v.y; a1.z += Hh * w1v.z; a1.w += Hh * w1v.w;
    }
    #pragma unroll
    for (int h = 0; h < 8; ++h) {
        float Hh = __shfl(H_b, h, 8);
        float4 w0 = w2q[(h + 8) * 16 + 2 * sub], w1v = w2q[(h + 8) * 16 + 2 * sub + 1];
        a0.x += Hh * w0.x; a0.y += Hh * w0.y; a0.z += Hh * w0.z; a0.w += Hh * w0.w;
        a1.x += Hh * w1v.x; a1.y += Hh * w1v.y; a1.z += Hh * w1v.z; a1.w += Hh * w1v.w;
    }
    float4 o0, o1;
    o0.x = own0.x * sigmoidf_(a0.x + 2.0f * bq0.x);
    o0.y = own0.y * sigmoidf_(a0.y + 2.0f * bq0.y);
    o0.z = own0.z * sigmoidf_(a0.z + 2.0f * bq0.z);
    o0.w = own0.w * sigmoidf_(a0.w + 2.0f * bq0.w);
    o1.x = own1.x * sigmoidf_(a1.x + 2.0f * bq1.x);
    o1.y = own1.y * sigmoidf_(a1.y + 2.0f * bq1.y);
    o1.z = own1.z * sigmoidf_(a1.z + 2.0f * bq1.z);
    o1.w = own1.w * sigmoidf_(a1.w + 2.0f * bq1.w);
    outse[(size_t)p * 16 + 2 * sub] = o0;
    outse[(size_t)p * 16 + 2 * sub + 1] = o1;

    // per-row stats for phase B (8B/neighbor there instead of 128B)
    float sm = (o0.x + o0.y + o0.z + o0.w) + (o1.x + o1.y + o1.z + o1.w);
    float sx = fmaxf(fmaxf(fmaxf(o0.x, o0.y), fmaxf(o0.z, o0.w)),
                     fmaxf(fmaxf(o1.x, o1.y), fmaxf(o1.z, o1.w)));
    #pragma unroll
    for (int m = 4; m >= 1; m >>= 1) {
        sm += __shfl_xor(sm, m);
        sx = fmaxf(sx, __shfl_xor(sx, m));
    }
    if (sub == 0) rowstat[p] = make_float2(sm * (1.0f / 64.0f), sx);
}

// Phase B: z[n] = (mean_k rowmean, max_k rowmax). 2 lanes per point.
__global__ __launch_bounds__(256) void kB(const int4* __restrict__ idxv,
        const float2* __restrict__ rowstat, float2* __restrict__ z, int n) {
    int t = blockIdx.x * 256 + threadIdx.x;
    int i = t >> 1, half = t & 1;
    if (i >= n) return;
    int4 a = idxv[(size_t)i * 4 + half * 2];
    int4 b = idxv[(size_t)i * 4 + half * 2 + 1];
    float2 s0 = rowstat[a.x], s1 = rowstat[a.y], s2 = rowstat[a.z], s3 = rowstat[a.w];
    float2 s4 = rowstat[b.x], s5 = rowstat[b.y], s6 = rowstat[b.z], s7 = rowstat[b.w];
    float zm = (s0.x + s1.x) + (s2.x + s3.x) + ((s4.x + s5.x) + (s6.x + s7.x));
    float zx = fmaxf(fmaxf(fmaxf(s0.y, s1.y), fmaxf(s2.y, s3.y)),
                     fmaxf(fmaxf(s4.y, s5.y), fmaxf(s6.y, s7.y)));
    zm += __shfl_xor(zm, 1);
    zx = fmaxf(zx, __shfl_xor(zx, 1));
    if (half == 0) z[i] = make_float2(zm * (1.0f / 16.0f), zx);
}

// Phase C (fused conv + scale): sig per point via LDS, then out = outse * sig.
// 128 points/block (782 blocks = 3/CU vs 391 = 1.5/CU): the conv phase is 27
// serial masked z-gathers per thread (L2-latency-bound); doubling block-level
// TLP hides more of it. The scale loop still uses all 256 threads.
__global__ __launch_bounds__(256) void kC(const int* __restrict__ conv_idx,
        const float* __restrict__ conv_w, const float2* __restrict__ z,
        const float4* __restrict__ outse, float4* __restrict__ out, int n) {
    __shared__ float cw[54];
    __shared__ float sgate[128];
    if (threadIdx.x < 54) cw[threadIdx.x] = conv_w[threadIdx.x];
    __syncthreads();
    int base = blockIdx.x * 128;
    int t = threadIdx.x;
    if (t < 128) {
        int i = base + t;
        if (i < n) {
            float acc = 0.0f;
            #pragma unroll
            for (int k = 0; k < 27; ++k) {
                int j = conv_idx[(size_t)i * 27 + k];   // branchless clamp + mask
                int jc = j >= 0 ? j : 0;
                float msk = j >= 0 ? 1.0f : 0.0f;
                float2 zz = z[jc];
                acc += msk * (zz.x * cw[2 * k] + zz.y * cw[2 * k + 1]);
            }
            sgate[t] = sigmoidf_(acc);
        }
    }
    __syncthreads();
    int npts = n - base; if (npts > 128) npts = 128;
    int tot = npts * 16;                            // float4s this block owns
    for (int q = t; q < tot; q += 256) {
        float s = sgate[q >> 4];
        float4 v = outse[(size_t)base * 16 + q];
        out[(size_t)base * 16 + q] = make_float4(v.x * s, v.y * s, v.z * s, v.w * s);
    }
}

extern "C" void kernel_launch(void* const* d_in, const int* in_sizes, int n_in,
                              void* d_out, int out_size, void* d_ws, size_t ws_size,
                              hipStream_t stream) {
    const float* x_F    = (const float*)d_in[0];
    const float* W1     = (const float*)d_in[1];
    const float* b1     = (const float*)d_in[2];
    const float* W2     = (const float*)d_in[3];
    const float* b2     = (const float*)d_in[4];
    const float* conv_w = (const float*)d_in[5];
    const int*   idx    = (const int*)d_in[6];
    const int*   cidx   = (const int*)d_in[7];
    int n = in_sizes[0] / CH;   // 100000

    char* ws = (char*)d_ws;
    size_t off = 0;
    uint2*  xb      = (uint2*)(ws + off);  off += (size_t)n * CH * 2;   // bf16 table
    float*  outse   = (float*)(ws + off);  off += (size_t)n * CH * 4;
    float2* rowstat = (float2*)(ws + off); off += (size_t)n * 8;
    float2* zz      = (float2*)(ws + off); off += (size_t)n * 8;

    int n16 = n * 16;
    kX<<<(n16 + 255) / 256, 256, 0, stream>>>((const float4*)x_F, xb, n16);
    int blkA = (n + 31) / 32;
    kA<<<blkA, 256, 0, stream>>>((const float4*)x_F, (const uint4*)xb,
                                 W1, b1, W2, b2, (const int2*)idx,
                                 (float4*)outse, rowstat, n);
    int blkB = (2 * n + 255) / 256;
    kB<<<blkB, 256, 0, stream>>>((const int4*)idx, rowstat, zz, n);
    int blkP = (n + 127) / 128;
    kC<<<blkP, 256, 0, stream>>>(cidx, conv_w, zz, (const float4*)outse,
                                 (float4*)d_out, n);
}